// Round 11
// baseline (466.248 us; speedup 1.0000x reference)
//
#include <hip/hip_runtime.h>
#include <hip/hip_bf16.h>

#define B 4
#define N 2048
#define D 2048
#define H 16
#define DH 128
#define NT 32  // N / 64 key tiles

typedef unsigned short u16;
typedef __attribute__((ext_vector_type(8))) short short8;   // 8 bf16 in 4 VGPRs
typedef __attribute__((ext_vector_type(4))) float floatx4;  // MFMA C/D frag

__device__ __forceinline__ u16 f2b(float f) {
    union { __hip_bfloat16 h; u16 u; } cv;
    cv.h = __float2bfloat16(f);
    return cv.u;
}

__device__ __forceinline__ floatx4 mfma16(short8 a, short8 b, floatx4 c) {
    return __builtin_amdgcn_mfma_f32_16x16x32_bf16(a, b, c, 0, 0, 0);
}

#if __has_builtin(__builtin_amdgcn_exp2f)
#define EXP2(x) __builtin_amdgcn_exp2f(x)
#else
#define EXP2(x) exp2f(x)
#endif

// async global->LDS, 16B per lane; LDS dest = wave-uniform base + lane*16
__device__ __forceinline__ void async16(const void* g, void* l) {
    __builtin_amdgcn_global_load_lds(
        (const __attribute__((address_space(1))) unsigned int*)g,
        (__attribute__((address_space(3))) unsigned int*)l, 16, 0, 0);
}

// ---------------------------------------------------------------- cvt_fused
// blocks [0,8192): x fp32 -> bf16.  blocks [8192,11264): W fp32 [k][n] ->
// Wt bf16 [z][n][k] (Wq folds log2(e)/sqrt(128)). One launch instead of two.
__global__ __launch_bounds__(256) void cvt_fused(const float* __restrict__ x,
                                                 const float* __restrict__ Wq,
                                                 const float* __restrict__ Wk,
                                                 const float* __restrict__ Wv,
                                                 u16* __restrict__ xb,
                                                 u16* __restrict__ wt) {
    __shared__ float tile[64][65];
    const int bx = blockIdx.x;
    if (bx < 8192) {
        size_t i = ((size_t)bx * 256 + threadIdx.x) * 8;
        float4 v0 = *(const float4*)&x[i];
        float4 v1 = *(const float4*)&x[i + 4];
        union { u16 u[8]; uint4 s; } pk;
        pk.u[0] = f2b(v0.x); pk.u[1] = f2b(v0.y); pk.u[2] = f2b(v0.z); pk.u[3] = f2b(v0.w);
        pk.u[4] = f2b(v1.x); pk.u[5] = f2b(v1.y); pk.u[6] = f2b(v1.z); pk.u[7] = f2b(v1.w);
        *(uint4*)&xb[i] = pk.s;
        return;
    }
    const int wi = bx - 8192;
    const int z = wi >> 10;
    const int rem = wi & 1023;
    const float* W = (z == 0) ? Wq : (z == 1) ? Wk : Wv;
    const float scl = (z == 0) ? 0.12751743342f : 1.0f;  // log2e/sqrt(128)
    const int k0 = (rem & 31) * 64, n0 = (rem >> 5) * 64;
    const int tr = threadIdx.x >> 4, tc = threadIdx.x & 15;
#pragma unroll
    for (int i = 0; i < 4; i++) {
        int kk = tr + 16 * i;
        float4 vv = *(const float4*)&W[(size_t)(k0 + kk) * D + n0 + tc * 4];
        tile[kk][tc * 4 + 0] = vv.x; tile[kk][tc * 4 + 1] = vv.y;
        tile[kk][tc * 4 + 2] = vv.z; tile[kk][tc * 4 + 3] = vv.w;
    }
    __syncthreads();
#pragma unroll
    for (int i = 0; i < 4; i++) {
        int nn = tr + 16 * i;
        union { u16 u[4]; ushort4 s; } pk;
#pragma unroll
        for (int j = 0; j < 4; j++) pk.u[j] = f2b(tile[tc * 4 + j][nn] * scl);
        *(ushort4*)&wt[(size_t)z * D * D + (size_t)(n0 + nn) * D + k0 + tc * 4] = pk.s;
    }
}

// ---------------------------------------------------------------- qkv_gemm
// (unchanged from round 9 — verified) 256x256, BK=64, 8 waves, rate-matched
// read spread, 3 A-bufs + 2 B-bufs = 160 KiB, 1 barrier/tile; V-blocks write
// V^T kappa2 directly via LDS-transpose epilogue.
#define KT 32          // K / BK = 2048/64
#define SGB __builtin_amdgcn_sched_group_barrier
__global__ __launch_bounds__(512, 2) void qkv_gemm(const u16* __restrict__ xb,
                                                   const u16* __restrict__ wt,
                                                   u16* __restrict__ qo,
                                                   u16* __restrict__ ko,
                                                   u16* __restrict__ vo) {
    // byte map: A bufs 3 x 32768 at 0/32768/65536; B bufs 2 x 32768 at
    // 98304/131072. Within a buf: [half:16384][row:128][16B slot s holds
    // logical slot s^(row&7)] (pre-swizzled staging source).
    __shared__ u16 lds[81920];  // 163840 B

    // XCD-aware bijective swizzle: XCD c gets a 16x6 tile rectangle.
    const int bid = blockIdx.x;
    const int c = bid & 7, i = bid >> 3;        // XCD, idx 0..95
    const int i6 = (i * 43) >> 8;               // i/6 exact for 0..95
    const int tm = ((c >> 2) << 4) + i6;        // 0..31
    const int tn = (c & 3) * 6 + (i - 6 * i6);  // 0..23

    const int t = threadIdx.x, lane = t & 63, w = t >> 6;
    const int wr = w >> 2, wc = w & 3;        // wave grid 2(M) x 4(N)
    const int q4 = lane >> 4, lr = lane & 15; // frag quad-row / row

    const int m0 = tm * 256;
    const int n0 = tn * 256;

    // per-thread pre-swizzled staging source offsets (elements)
    unsigned aoff[2][2], boff[2][2];  // [half][issue]
#pragma unroll
    for (int ii = 0; ii < 2; ii++) {
        const int off = ii * 8192 + w * 1024 + lane * 16;  // linear byte in half-tile
        const int row = off >> 7;          // 0..127
        const int s = (off >> 4) & 7;      // 16B slot 0..7
        const int col = ((s ^ (row & 7))) * 8;
#pragma unroll
        for (int h = 0; h < 2; h++) {
            aoff[h][ii] = (unsigned)((m0 + h * 128 + row) * D + col);
            boff[h][ii] = (unsigned)((n0 + h * 128 + row) * D + col);
        }
    }

    // per-lane LDS read base components. Frag rows are == lr (mod 8) for all
    // mf/nf (16-row strides) -> swizzle slot (ks*4+q4)^(lr&7), ks in {0,1}.
    const unsigned cb0 = (unsigned)(((0 * 4 + q4) ^ (lr & 7)) * 16);
    const unsigned cb1 = (unsigned)(((1 * 4 + q4) ^ (lr & 7)) * 16);
    const unsigned aC0 = (unsigned)(wr * 16384 + lr * 128) + cb0;
    const unsigned aC1 = (unsigned)(wr * 16384 + lr * 128) + cb1;
    const unsigned bC0 = (unsigned)((wc >> 1) * 16384 + (wc & 1) * 8192 + lr * 128) + cb0;
    const unsigned bC1 = (unsigned)((wc >> 1) * 16384 + (wc & 1) * 8192 + lr * 128) + cb1;

#define STAGE_A(bufoff, h, j) {                                                           \
    async16(xb + aoff[h][0] + (unsigned)(j) * 64,                                         \
            (char*)lds + (bufoff) + (h) * 16384 + w * 1024);                              \
    async16(xb + aoff[h][1] + (unsigned)(j) * 64,                                         \
            (char*)lds + (bufoff) + (h) * 16384 + 8192 + w * 1024); }
#define STAGE_B(bufoff, h, j) {                                                           \
    async16(wt + boff[h][0] + (unsigned)(j) * 64,                                         \
            (char*)lds + (bufoff) + (h) * 16384 + w * 1024);                              \
    async16(wt + boff[h][1] + (unsigned)(j) * 64,                                         \
            (char*)lds + (bufoff) + (h) * 16384 + 8192 + w * 1024); }
#define BAR() __builtin_amdgcn_s_barrier()
#define DSR(off) (*(const short8*)((const char*)lds + (off)))

    floatx4 acc[8][4];
#pragma unroll
    for (int x = 0; x < 8; x++)
#pragma unroll
        for (int j = 0; j < 4; j++) acc[x][j] = (floatx4){0.f, 0.f, 0.f, 0.f};

    // ---- prologue: A(0)->buf0, B(0)->Bbuf0, A(1)->buf1 (12 loads/thread)
    STAGE_A(0u, 0, 0); STAGE_A(0u, 1, 0);
    STAGE_B(98304u, 0, 0); STAGE_B(98304u, 1, 0);
    STAGE_A(32768u, 0, 1); STAGE_A(32768u, 1, 1);
    asm volatile("s_waitcnt vmcnt(4)" ::: "memory");  // A(0),B(0) landed; A(1) in flight
    BAR();

    unsigned aOffR = 0u;      // read buf  = (g%3)*32768
    unsigned aOffW = 65536u;  // write buf = ((g+2)%3)*32768

    for (int g = 0; g < KT; g++) {
        const unsigned bR = 98304u + (unsigned)((g & 1) << 15);
        const unsigned bW = 98304u + (unsigned)(((g + 1) & 1) << 15);

        // ---- staging first (fenced): B(g+1), A(g+2)
        if (g + 1 < KT) { STAGE_B(bW, 0, g + 1); STAGE_B(bW, 1, g + 1); }
        if (g + 2 < KT) { STAGE_A(aOffW, 0, g + 2); STAGE_A(aOffW, 1, g + 2); }
        __builtin_amdgcn_sched_barrier(0);

        const unsigned aB0 = aOffR + aC0, aB1 = aOffR + aC1;
        const unsigned bB0 = bR + bC0, bB1 = bR + bC1;

        short8 a0k0[4], a0k1[4], a1k0[4], a1k1[4];
        short8 b0k0[2], b0k1[2], b1k0[2], b1k1[2];

        // G1(6): b0k0, a0k0
        b0k0[0] = DSR(bB0);        b0k0[1] = DSR(bB0 + 2048);
#pragma unroll
        for (int mf = 0; mf < 4; mf++) a0k0[mf] = DSR(aB0 + mf * 2048);
        // G2(4): a1k0
#pragma unroll
        for (int mf = 0; mf < 4; mf++) a1k0[mf] = DSR(aB0 + 8192 + mf * 2048);
        // C1: Q00k0
#pragma unroll
        for (int nf = 0; nf < 2; nf++)
#pragma unroll
            for (int mf = 0; mf < 4; mf++)
                acc[mf][nf] = mfma16(a0k0[mf], b0k0[nf], acc[mf][nf]);
        // G3(2): b1k0
        b1k0[0] = DSR(bB0 + 4096); b1k0[1] = DSR(bB0 + 6144);
        // C2: Q10k0
#pragma unroll
        for (int nf = 0; nf < 2; nf++)
#pragma unroll
            for (int mf = 0; mf < 4; mf++)
                acc[4 + mf][nf] = mfma16(a1k0[mf], b0k0[nf], acc[4 + mf][nf]);
        // G4(6): b0k1, a0k1
        b0k1[0] = DSR(bB1);        b0k1[1] = DSR(bB1 + 2048);
#pragma unroll
        for (int mf = 0; mf < 4; mf++) a0k1[mf] = DSR(aB1 + mf * 2048);
        // C3: Q11k0
#pragma unroll
        for (int nf = 0; nf < 2; nf++)
#pragma unroll
            for (int mf = 0; mf < 4; mf++)
                acc[4 + mf][2 + nf] = mfma16(a1k0[mf], b1k0[nf], acc[4 + mf][2 + nf]);
        // G5(4): a1k1
#pragma unroll
        for (int mf = 0; mf < 4; mf++) a1k1[mf] = DSR(aB1 + 8192 + mf * 2048);
        // C4: Q01k0
#pragma unroll
        for (int nf = 0; nf < 2; nf++)
#pragma unroll
            for (int mf = 0; mf < 4; mf++)
                acc[mf][2 + nf] = mfma16(a0k0[mf], b1k0[nf], acc[mf][2 + nf]);
        // G6(2): b1k1
        b1k1[0] = DSR(bB1 + 4096); b1k1[1] = DSR(bB1 + 6144);
        // C5: Q00k1
#pragma unroll
        for (int nf = 0; nf < 2; nf++)
#pragma unroll
            for (int mf = 0; mf < 4; mf++)
                acc[mf][nf] = mfma16(a0k1[mf], b0k1[nf], acc[mf][nf]);
        // C6: Q10k1
#pragma unroll
        for (int nf = 0; nf < 2; nf++)
#pragma unroll
            for (int mf = 0; mf < 4; mf++)
                acc[4 + mf][nf] = mfma16(a1k1[mf], b0k1[nf], acc[4 + mf][nf]);
        // C7: Q11k1
#pragma unroll
        for (int nf = 0; nf < 2; nf++)
#pragma unroll
            for (int mf = 0; mf < 4; mf++)
                acc[4 + mf][2 + nf] = mfma16(a1k1[mf], b1k1[nf], acc[4 + mf][2 + nf]);
        // C8: Q01k1
#pragma unroll
        for (int nf = 0; nf < 2; nf++)
#pragma unroll
            for (int mf = 0; mf < 4; mf++)
                acc[mf][2 + nf] = mfma16(a0k1[mf], b1k1[nf], acc[mf][2 + nf]);

        // ---- schedule template: rate-matched DS/MFMA interleave
        SGB(0x100, 10, 0);  // G1+G2
        SGB(0x008,  8, 0);  // C1
        SGB(0x100,  2, 0);  // G3
        SGB(0x008,  8, 0);  // C2
        SGB(0x100,  6, 0);  // G4
        SGB(0x008,  8, 0);  // C3
        SGB(0x100,  4, 0);  // G5
        SGB(0x008,  8, 0);  // C4
        SGB(0x100,  2, 0);  // G6
        SGB(0x008,  8, 0);  // C5
        SGB(0x008,  8, 0);  // C6
        SGB(0x008,  8, 0);  // C7
        SGB(0x008,  8, 0);  // C8

        // ---- tile boundary: counted wait + single barrier
        if (g == KT - 2) { asm volatile("s_waitcnt vmcnt(0)" ::: "memory"); }
        else if (g < KT - 2) { asm volatile("s_waitcnt vmcnt(4)" ::: "memory"); }
        if (g + 1 < KT) BAR();

        // rotate A buffers (mod 3)
        aOffR = (aOffR == 65536u) ? 0u : aOffR + 32768u;
        aOffW = (aOffW == 65536u) ? 0u : aOffW + 32768u;
    }

    const int z = tn >> 3;
    if (z < 2) {
        // ---- Q/K epilogue: direct scatter (unchanged, verified)
        u16* dst = (z == 0) ? qo : ko;
        const int c2b = (tn & 7) * 256 + wc * 64;
        const int grb = tm * 256 + wr * 128;
#pragma unroll
        for (int mf = 0; mf < 8; mf++)
#pragma unroll
            for (int nf = 0; nf < 4; nf++)
#pragma unroll
                for (int r = 0; r < 4; r++) {
                    int gr = grb + mf * 16 + q4 * 4 + r;
                    int c2 = c2b + nf * 16 + lr;
                    int b_ = gr >> 11, n_ = gr & (N - 1);
                    int head = c2 >> 7, dcol = c2 & 127;
                    dst[((size_t)(b_ * H + head) * N + n_) * DH + dcol] = f2b(acc[mf][nf][r]);
                }
    } else {
        // ---- V epilogue: LDS transpose + inverse-kappa2, coalesced vt write.
        __syncthreads();  // waves may still be reading A/B bufs of tile 31
        char* Vl = (char*)lds;  // 128 KB of the 160 KB
#pragma unroll
        for (int mf = 0; mf < 8; mf++) {
            const int granbase = wr * 32 + (mf >> 2) * 16 + ((mf & 3) >> 1) * 8
                               + ((mf & 3) & 1) + 2 * q4;
#pragma unroll
            for (int nf = 0; nf < 4; nf++) {
                int row = wc * 64 + nf * 16 + lr;
                union { u16 u[4]; unsigned long long qv; } pk;
#pragma unroll
                for (int r = 0; r < 4; r++) pk.u[r] = f2b(acc[mf][nf][r]);
                int gran = granbase ^ (row & 7);
                *(unsigned long long*)(Vl + row * 512 + gran * 8) = pk.qv;
            }
        }
        __syncthreads();
        // read out: one wave = one row (64 granules), 8B/lane, coalesced store
        const int bhb = (tm >> 3) * 16 + 2 * (tn & 7);
        const int nbase = (tm & 7) * 256;
#pragma unroll
        for (int pp = 0; pp < 32; pp++) {
            int idx = pp * 512 + t;
            int row = idx >> 6, g = idx & 63;
            unsigned long long v =
                *(const unsigned long long*)(Vl + row * 512 + ((g ^ (row & 7)) * 8));
            int bh = bhb + (row >> 7), dd = row & 127;
            *(unsigned long long*)&vo[((size_t)bh * DH + dd) * N + nbase + g * 4] = v;
        }
    }
#undef STAGE_A
#undef STAGE_B
#undef BAR
#undef DSR
}

// ---------------------------------------------------------------- attn
// v5: rt=4 (64 q-rows/wave), 4 waves x 256 rows/block, 512 blocks.
// Diagnosis (r10): attn is LDS-READ-bound — v3 had 8 waves/CU each reading
// the identical K/V frags (256 b128/CU/tile = 3072 cyc vs 620 MFMA). v4's
// S/PV pipeline couldn't help (wrong pipe). Fix: double rows/wave so each
// K/V b128 read feeds 4 MFMAs instead of 2 -> per-CU LDS halves to 1536cy;
// per-SIMD VALU unchanged (1 wave x 64 exp2 == 2 waves x 32).
// Loop = verified r8-v3 skeleton (K/V double-buffer, 1 barrier/tile, no
// cross-tile pipeline). Registers: o[4][8]=128 + af[4][4]=64 + PA/paw ~80
// -> ~310 VGPR, fits 512 file, 1 wave/SIMD, 1 block/CU, 2 rounds.
// XCD map: each XCD's resident blocks share 4 bh -> 2 MB K/V in its L2.
#define FMAX2 17.312340491f   // 12 * log2(e)
__global__ __launch_bounds__(256, 1) void attn_kernel(const u16* __restrict__ q,
                                                      const u16* __restrict__ k,
                                                      const u16* __restrict__ vt,
                                                      float* __restrict__ out) {
    // LDS: Ks[2][64 key][128 d] at 0/16384 (16B-slot swz ^(row&15))
    //      Vts[2][128 dd][64 kappa2] at 32768/49152 (8-slot swz ^(dd&7))
    //      epilogue: Ls[256] f32 aliases bytes 0..1024 (kbuf0, dead by then)
    __shared__ __align__(16) char smem[65536];   // 64 KB

    const int beta = blockIdx.x;                  // 0..511
    const int bh = (beta & 7) + 8 * (beta >> 6);  // bijective; XCD-local bh
    const int qt = (beta >> 3) & 7;               // 256-row q tile
    const int t = threadIdx.x;
    const int w = t >> 6, lane = t & 63;          // w = 64-row quarter
    const int q4 = lane >> 4, lr = lane & 15;

    // Q fragments: rows 64w+16rt+lr, d = 32ks+8q4 (B-operand of swapped S)
    const size_t qbase = ((size_t)bh * N + (size_t)qt * 256) * DH;
    short8 af[4][4];
#pragma unroll
    for (int rt = 0; rt < 4; rt++)
#pragma unroll
        for (int ks = 0; ks < 4; ks++)
            af[rt][ks] = *(const short8*)&q[qbase + (size_t)(64 * w + 16 * rt + lr) * DH
                                            + ks * 32 + q4 * 8];

    float lrow[4] = {0.f, 0.f, 0.f, 0.f};
    floatx4 o[4][8];
#pragma unroll
    for (int rt = 0; rt < 4; rt++)
#pragma unroll
        for (int cv = 0; cv < 8; cv++) o[rt][cv] = (floatx4){0.f, 0.f, 0.f, 0.f};

    // staging source offsets (pre-swizzled; 16B granules) — verified
    const u16* kpB = k + (size_t)bh * N * DH;
    const u16* vpB = vt + (size_t)bh * DH * N;
    unsigned koff[4], voff[4];
#pragma unroll
    for (int c = 0; c < 4; c++) {
        int grp = 4 * w + c;
        int krow = 4 * grp + (lane >> 4);
        int kg = (lane & 15) ^ (krow & 15);
        koff[c] = (unsigned)(krow * DH + kg * 8);
        int vrow = 8 * grp + (lane >> 3);
        int vg = (lane & 7) ^ (vrow & 7);
        voff[c] = (unsigned)(vrow * N + vg * 8);
    }

    // hoisted LDS read addresses (buffer 0); toggled ^16384 per tile — verified
    unsigned kaddr[4];
#pragma unroll
    for (int ks = 0; ks < 4; ks++)
        kaddr[ks] = (unsigned)(lr * 256 + (((4 * ks + q4) ^ lr) * 16));
    unsigned vaddr[2];
#pragma unroll
    for (int a = 0; a < 2; a++)
        vaddr[a] = (unsigned)(32768 + lr * 128 + (((4 * a + q4) ^ (lr & 7)) * 16));

    // prologue: stage tile 0 into buffer 0
#pragma unroll
    for (int c = 0; c < 4; c++) {
        async16(kpB + koff[c], smem + (4 * w + c) * 1024);
        async16(vpB + voff[c], smem + 32768 + (4 * w + c) * 1024);
    }

    for (int kt = 0; kt < NT; kt++) {
        __syncthreads();  // vmcnt(0)+barrier: K/V(kt) visible; other buffer free

        // prefetch kt+1 (in flight until next barrier's drain)
        if (kt + 1 < NT) {
            const int nb = (kt + 1) & 1;
#pragma unroll
            for (int c = 0; c < 4; c++) {
                async16(kpB + koff[c] + (unsigned)(kt + 1) * 64 * DH,
                        smem + nb * 16384 + (4 * w + c) * 1024);
                async16(vpB + voff[c] + (unsigned)(kt + 1) * 64,
                        smem + 32768 + nb * 16384 + (4 * w + c) * 1024);
            }
        }

        // ---- S^T = K Q^T + fused softmax (P stays in registers)
        unsigned paw[4][4][2];  // [rt][ct][r-pair]
#pragma unroll
        for (int ct = 0; ct < 4; ct++) {
            short8 bf[4];
#pragma unroll
            for (int ks = 0; ks < 4; ks++)
                bf[ks] = *(const short8*)(smem + kaddr[ks] + ct * 4096);
#pragma unroll
            for (int rt = 0; rt < 4; rt++) {
                floatx4 s = (floatx4){0.f, 0.f, 0.f, 0.f};
#pragma unroll
                for (int ks = 0; ks < 4; ks++) s = mfma16(bf[ks], af[rt][ks], s);
                float p0 = EXP2(s[0] - FMAX2), p1 = EXP2(s[1] - FMAX2);
                float p2 = EXP2(s[2] - FMAX2), p3 = EXP2(s[3] - FMAX2);
                lrow[rt] += (p0 + p1) + (p2 + p3);
                paw[rt][ct][0] = (unsigned)f2b(p0) | ((unsigned)f2b(p1) << 16);
                paw[rt][ct][1] = (unsigned)f2b(p2) | ((unsigned)f2b(p3) << 16);
            }
        }
        // pack PA[rt][a]: element j = key 32a + 16(j>>2) + 4q4 + (j&3)
        short8 PA[4][2];
#pragma unroll
        for (int rt = 0; rt < 4; rt++)
#pragma unroll
            for (int a = 0; a < 2; a++) {
                union { unsigned uu[4]; short8 s8; } cv_;
                cv_.uu[0] = paw[rt][2 * a][0];     cv_.uu[1] = paw[rt][2 * a][1];
                cv_.uu[2] = paw[rt][2 * a + 1][0]; cv_.uu[3] = paw[rt][2 * a + 1][1];
                PA[rt][a] = cv_.s8;
            }

        // ---- PV: o[rt][ctv] += sum_a PA[rt][a] x V_a (one b128 per (ctv,a))
#pragma unroll
        for (int ctv = 0; ctv < 8; ctv++) {
#pragma unroll
            for (int a = 0; a < 2; a++) {
                short8 bv = *(const short8*)(smem + vaddr[a] + ctv * 2048);
#pragma unroll
                for (int rt = 0; rt < 4; rt++)
                    o[rt][ctv] = mfma16(PA[rt][a], bv, o[rt][ctv]);
            }
        }

        // toggle double buffers
#pragma unroll
        for (int ks = 0; ks < 4; ks++) kaddr[ks] ^= 16384u;
        vaddr[0] ^= 16384u; vaddr[1] ^= 16384u;
    }

    // ---- epilogue: row sums; q4-butterfly completes 64 keys; redistribute.
    // Ls aliases kbuf0 bytes 0..1024 (tile 31 reads kbuf1/vbuf — disjoint).
    float* Ls = (float*)smem;  // [256]
#pragma unroll
    for (int rt = 0; rt < 4; rt++) {
        float s = lrow[rt];
        s += __shfl_xor(s, 16);
        s += __shfl_xor(s, 32);
        if (q4 == 0) Ls[64 * w + 16 * rt + lr] = s;
    }
    __syncthreads();
    const size_t obase = ((size_t)bh * N + (size_t)qt * 256) * DH;
#pragma unroll
    for (int rt = 0; rt < 4; rt++) {
        floatx4 inv4;
#pragma unroll
        for (int r = 0; r < 4; r++)
            inv4[r] = 1.f / Ls[64 * w + 16 * rt + 4 * q4 + r];
#pragma unroll
        for (int ctv = 0; ctv < 8; ctv++) {
            int dd = 16 * ctv + lr;
#pragma unroll
            for (int r = 0; r < 4; r++) {
                int row = 64 * w + 16 * rt + 4 * q4 + r;
                out[obase + (size_t)row * DH + dd] = o[rt][ctv][r] * inv4[r];
            }
        }
    }
}

// ---------------------------------------------------------------- launch
extern "C" void kernel_launch(void* const* d_in, const int* in_sizes, int n_in,
                              void* d_out, int out_size, void* d_ws, size_t ws_size,
                              hipStream_t stream) {
    const float* x  = (const float*)d_in[0];
    const float* Wq = (const float*)d_in[1];
    const float* Wk = (const float*)d_in[2];
    const float* Wv = (const float*)d_in[3];
    float* out = (float*)d_out;
    char* ws = (char*)d_ws;

    u16* xb = (u16*)(ws);                  // 32 MB  bf16 X
    u16* wt = (u16*)(ws + 33554432);       // 24 MB  bf16 W^T x3 (Wq scaled)
    u16* qb = (u16*)(ws + 58720256);       // 32 MB  Q bf16 [bh][n][d]
    u16* kb = (u16*)(ws + 92274688);       // 32 MB  K bf16 [bh][n][d]
    u16* vtb = (u16*)(ws + 125829120);     // 32 MB  V^T kappa2 [bh][d][n] (direct)

    cvt_fused<<<dim3(11264), dim3(256), 0, stream>>>(x, Wq, Wk, Wv, xb, wt);
    qkv_gemm<<<dim3(768), dim3(512), 0, stream>>>(xb, wt, qb, kb, vtb);
    attn_kernel<<<dim3(512), dim3(256), 0, stream>>>(qb, kb, vtb, out);
}

// Round 12
// 439.388 us; speedup vs baseline: 1.0611x; 1.0611x over previous
//
#include <hip/hip_runtime.h>
#include <hip/hip_bf16.h>

#define B 4
#define N 2048
#define D 2048
#define H 16
#define DH 128
#define NT 32  // N / 64 key tiles

typedef unsigned short u16;
typedef __attribute__((ext_vector_type(8))) short short8;   // 8 bf16 in 4 VGPRs
typedef __attribute__((ext_vector_type(4))) float floatx4;  // MFMA C/D frag

__device__ __forceinline__ u16 f2b(float f) {
    union { __hip_bfloat16 h; u16 u; } cv;
    cv.h = __float2bfloat16(f);
    return cv.u;
}

__device__ __forceinline__ floatx4 mfma16(short8 a, short8 b, floatx4 c) {
    return __builtin_amdgcn_mfma_f32_16x16x32_bf16(a, b, c, 0, 0, 0);
}

#if __has_builtin(__builtin_amdgcn_exp2f)
#define EXP2(x) __builtin_amdgcn_exp2f(x)
#else
#define EXP2(x) exp2f(x)
#endif

// async global->LDS, 16B per lane; LDS dest = wave-uniform base + lane*16
__device__ __forceinline__ void async16(const void* g, void* l) {
    __builtin_amdgcn_global_load_lds(
        (const __attribute__((address_space(1))) unsigned int*)g,
        (__attribute__((address_space(3))) unsigned int*)l, 16, 0, 0);
}

// ---------------------------------------------------------------- cvt_fused
// blocks [0,8192): x fp32 -> bf16.  blocks [8192,11264): W fp32 [k][n] ->
// Wt bf16 [z][n][k] (Wq folds log2(e)/sqrt(128)). One launch instead of two.
__global__ __launch_bounds__(256) void cvt_fused(const float* __restrict__ x,
                                                 const float* __restrict__ Wq,
                                                 const float* __restrict__ Wk,
                                                 const float* __restrict__ Wv,
                                                 u16* __restrict__ xb,
                                                 u16* __restrict__ wt) {
    __shared__ float tile[64][65];
    const int bx = blockIdx.x;
    if (bx < 8192) {
        size_t i = ((size_t)bx * 256 + threadIdx.x) * 8;
        float4 v0 = *(const float4*)&x[i];
        float4 v1 = *(const float4*)&x[i + 4];
        union { u16 u[8]; uint4 s; } pk;
        pk.u[0] = f2b(v0.x); pk.u[1] = f2b(v0.y); pk.u[2] = f2b(v0.z); pk.u[3] = f2b(v0.w);
        pk.u[4] = f2b(v1.x); pk.u[5] = f2b(v1.y); pk.u[6] = f2b(v1.z); pk.u[7] = f2b(v1.w);
        *(uint4*)&xb[i] = pk.s;
        return;
    }
    const int wi = bx - 8192;
    const int z = wi >> 10;
    const int rem = wi & 1023;
    const float* W = (z == 0) ? Wq : (z == 1) ? Wk : Wv;
    const float scl = (z == 0) ? 0.12751743342f : 1.0f;  // log2e/sqrt(128)
    const int k0 = (rem & 31) * 64, n0 = (rem >> 5) * 64;
    const int tr = threadIdx.x >> 4, tc = threadIdx.x & 15;
#pragma unroll
    for (int i = 0; i < 4; i++) {
        int kk = tr + 16 * i;
        float4 vv = *(const float4*)&W[(size_t)(k0 + kk) * D + n0 + tc * 4];
        tile[kk][tc * 4 + 0] = vv.x; tile[kk][tc * 4 + 1] = vv.y;
        tile[kk][tc * 4 + 2] = vv.z; tile[kk][tc * 4 + 3] = vv.w;
    }
    __syncthreads();
#pragma unroll
    for (int i = 0; i < 4; i++) {
        int nn = tr + 16 * i;
        union { u16 u[4]; ushort4 s; } pk;
#pragma unroll
        for (int j = 0; j < 4; j++) pk.u[j] = f2b(tile[tc * 4 + j][nn] * scl);
        *(ushort4*)&wt[(size_t)z * D * D + (size_t)(n0 + nn) * D + k0 + tc * 4] = pk.s;
    }
}

// ---------------------------------------------------------------- qkv_gemm
// (unchanged from round 9 — verified) 256x256, BK=64, 8 waves, rate-matched
// read spread, 3 A-bufs + 2 B-bufs = 160 KiB, 1 barrier/tile; V-blocks write
// V^T kappa2 directly via LDS-transpose epilogue.
#define KT 32          // K / BK = 2048/64
#define SGB __builtin_amdgcn_sched_group_barrier
__global__ __launch_bounds__(512, 2) void qkv_gemm(const u16* __restrict__ xb,
                                                   const u16* __restrict__ wt,
                                                   u16* __restrict__ qo,
                                                   u16* __restrict__ ko,
                                                   u16* __restrict__ vo) {
    // byte map: A bufs 3 x 32768 at 0/32768/65536; B bufs 2 x 32768 at
    // 98304/131072. Within a buf: [half:16384][row:128][16B slot s holds
    // logical slot s^(row&7)] (pre-swizzled staging source).
    __shared__ u16 lds[81920];  // 163840 B

    // XCD-aware bijective swizzle: XCD c gets a 16x6 tile rectangle.
    const int bid = blockIdx.x;
    const int c = bid & 7, i = bid >> 3;        // XCD, idx 0..95
    const int i6 = (i * 43) >> 8;               // i/6 exact for 0..95
    const int tm = ((c >> 2) << 4) + i6;        // 0..31
    const int tn = (c & 3) * 6 + (i - 6 * i6);  // 0..23

    const int t = threadIdx.x, lane = t & 63, w = t >> 6;
    const int wr = w >> 2, wc = w & 3;        // wave grid 2(M) x 4(N)
    const int q4 = lane >> 4, lr = lane & 15; // frag quad-row / row

    const int m0 = tm * 256;
    const int n0 = tn * 256;

    // per-thread pre-swizzled staging source offsets (elements)
    unsigned aoff[2][2], boff[2][2];  // [half][issue]
#pragma unroll
    for (int ii = 0; ii < 2; ii++) {
        const int off = ii * 8192 + w * 1024 + lane * 16;  // linear byte in half-tile
        const int row = off >> 7;          // 0..127
        const int s = (off >> 4) & 7;      // 16B slot 0..7
        const int col = ((s ^ (row & 7))) * 8;
#pragma unroll
        for (int h = 0; h < 2; h++) {
            aoff[h][ii] = (unsigned)((m0 + h * 128 + row) * D + col);
            boff[h][ii] = (unsigned)((n0 + h * 128 + row) * D + col);
        }
    }

    // per-lane LDS read base components. Frag rows are == lr (mod 8) for all
    // mf/nf (16-row strides) -> swizzle slot (ks*4+q4)^(lr&7), ks in {0,1}.
    const unsigned cb0 = (unsigned)(((0 * 4 + q4) ^ (lr & 7)) * 16);
    const unsigned cb1 = (unsigned)(((1 * 4 + q4) ^ (lr & 7)) * 16);
    const unsigned aC0 = (unsigned)(wr * 16384 + lr * 128) + cb0;
    const unsigned aC1 = (unsigned)(wr * 16384 + lr * 128) + cb1;
    const unsigned bC0 = (unsigned)((wc >> 1) * 16384 + (wc & 1) * 8192 + lr * 128) + cb0;
    const unsigned bC1 = (unsigned)((wc >> 1) * 16384 + (wc & 1) * 8192 + lr * 128) + cb1;

#define STAGE_A(bufoff, h, j) {                                                           \
    async16(xb + aoff[h][0] + (unsigned)(j) * 64,                                         \
            (char*)lds + (bufoff) + (h) * 16384 + w * 1024);                              \
    async16(xb + aoff[h][1] + (unsigned)(j) * 64,                                         \
            (char*)lds + (bufoff) + (h) * 16384 + 8192 + w * 1024); }
#define STAGE_B(bufoff, h, j) {                                                           \
    async16(wt + boff[h][0] + (unsigned)(j) * 64,                                         \
            (char*)lds + (bufoff) + (h) * 16384 + w * 1024);                              \
    async16(wt + boff[h][1] + (unsigned)(j) * 64,                                         \
            (char*)lds + (bufoff) + (h) * 16384 + 8192 + w * 1024); }
#define BAR() __builtin_amdgcn_s_barrier()
#define DSR(off) (*(const short8*)((const char*)lds + (off)))

    floatx4 acc[8][4];
#pragma unroll
    for (int x = 0; x < 8; x++)
#pragma unroll
        for (int j = 0; j < 4; j++) acc[x][j] = (floatx4){0.f, 0.f, 0.f, 0.f};

    // ---- prologue: A(0)->buf0, B(0)->Bbuf0, A(1)->buf1 (12 loads/thread)
    STAGE_A(0u, 0, 0); STAGE_A(0u, 1, 0);
    STAGE_B(98304u, 0, 0); STAGE_B(98304u, 1, 0);
    STAGE_A(32768u, 0, 1); STAGE_A(32768u, 1, 1);
    asm volatile("s_waitcnt vmcnt(4)" ::: "memory");  // A(0),B(0) landed; A(1) in flight
    BAR();

    unsigned aOffR = 0u;      // read buf  = (g%3)*32768
    unsigned aOffW = 65536u;  // write buf = ((g+2)%3)*32768

    for (int g = 0; g < KT; g++) {
        const unsigned bR = 98304u + (unsigned)((g & 1) << 15);
        const unsigned bW = 98304u + (unsigned)(((g + 1) & 1) << 15);

        // ---- staging first (fenced): B(g+1), A(g+2)
        if (g + 1 < KT) { STAGE_B(bW, 0, g + 1); STAGE_B(bW, 1, g + 1); }
        if (g + 2 < KT) { STAGE_A(aOffW, 0, g + 2); STAGE_A(aOffW, 1, g + 2); }
        __builtin_amdgcn_sched_barrier(0);

        const unsigned aB0 = aOffR + aC0, aB1 = aOffR + aC1;
        const unsigned bB0 = bR + bC0, bB1 = bR + bC1;

        short8 a0k0[4], a0k1[4], a1k0[4], a1k1[4];
        short8 b0k0[2], b0k1[2], b1k0[2], b1k1[2];

        // G1(6): b0k0, a0k0
        b0k0[0] = DSR(bB0);        b0k0[1] = DSR(bB0 + 2048);
#pragma unroll
        for (int mf = 0; mf < 4; mf++) a0k0[mf] = DSR(aB0 + mf * 2048);
        // G2(4): a1k0
#pragma unroll
        for (int mf = 0; mf < 4; mf++) a1k0[mf] = DSR(aB0 + 8192 + mf * 2048);
        // C1: Q00k0
#pragma unroll
        for (int nf = 0; nf < 2; nf++)
#pragma unroll
            for (int mf = 0; mf < 4; mf++)
                acc[mf][nf] = mfma16(a0k0[mf], b0k0[nf], acc[mf][nf]);
        // G3(2): b1k0
        b1k0[0] = DSR(bB0 + 4096); b1k0[1] = DSR(bB0 + 6144);
        // C2: Q10k0
#pragma unroll
        for (int nf = 0; nf < 2; nf++)
#pragma unroll
            for (int mf = 0; mf < 4; mf++)
                acc[4 + mf][nf] = mfma16(a1k0[mf], b0k0[nf], acc[4 + mf][nf]);
        // G4(6): b0k1, a0k1
        b0k1[0] = DSR(bB1);        b0k1[1] = DSR(bB1 + 2048);
#pragma unroll
        for (int mf = 0; mf < 4; mf++) a0k1[mf] = DSR(aB1 + mf * 2048);
        // C3: Q11k0
#pragma unroll
        for (int nf = 0; nf < 2; nf++)
#pragma unroll
            for (int mf = 0; mf < 4; mf++)
                acc[4 + mf][2 + nf] = mfma16(a1k0[mf], b1k0[nf], acc[4 + mf][2 + nf]);
        // G5(4): a1k1
#pragma unroll
        for (int mf = 0; mf < 4; mf++) a1k1[mf] = DSR(aB1 + 8192 + mf * 2048);
        // C4: Q01k0
#pragma unroll
        for (int nf = 0; nf < 2; nf++)
#pragma unroll
            for (int mf = 0; mf < 4; mf++)
                acc[mf][2 + nf] = mfma16(a0k0[mf], b1k0[nf], acc[mf][2 + nf]);
        // G6(2): b1k1
        b1k1[0] = DSR(bB1 + 4096); b1k1[1] = DSR(bB1 + 6144);
        // C5: Q00k1
#pragma unroll
        for (int nf = 0; nf < 2; nf++)
#pragma unroll
            for (int mf = 0; mf < 4; mf++)
                acc[mf][nf] = mfma16(a0k1[mf], b0k1[nf], acc[mf][nf]);
        // C6: Q10k1
#pragma unroll
        for (int nf = 0; nf < 2; nf++)
#pragma unroll
            for (int mf = 0; mf < 4; mf++)
                acc[4 + mf][nf] = mfma16(a1k1[mf], b0k1[nf], acc[4 + mf][nf]);
        // C7: Q11k1
#pragma unroll
        for (int nf = 0; nf < 2; nf++)
#pragma unroll
            for (int mf = 0; mf < 4; mf++)
                acc[4 + mf][2 + nf] = mfma16(a1k1[mf], b1k1[nf], acc[4 + mf][2 + nf]);
        // C8: Q01k1
#pragma unroll
        for (int nf = 0; nf < 2; nf++)
#pragma unroll
            for (int mf = 0; mf < 4; mf++)
                acc[mf][2 + nf] = mfma16(a0k1[mf], b1k1[nf], acc[mf][2 + nf]);

        // ---- schedule template: rate-matched DS/MFMA interleave
        SGB(0x100, 10, 0);  // G1+G2
        SGB(0x008,  8, 0);  // C1
        SGB(0x100,  2, 0);  // G3
        SGB(0x008,  8, 0);  // C2
        SGB(0x100,  6, 0);  // G4
        SGB(0x008,  8, 0);  // C3
        SGB(0x100,  4, 0);  // G5
        SGB(0x008,  8, 0);  // C4
        SGB(0x100,  2, 0);  // G6
        SGB(0x008,  8, 0);  // C5
        SGB(0x008,  8, 0);  // C6
        SGB(0x008,  8, 0);  // C7
        SGB(0x008,  8, 0);  // C8

        // ---- tile boundary: counted wait + single barrier
        if (g == KT - 2) { asm volatile("s_waitcnt vmcnt(0)" ::: "memory"); }
        else if (g < KT - 2) { asm volatile("s_waitcnt vmcnt(4)" ::: "memory"); }
        if (g + 1 < KT) BAR();

        // rotate A buffers (mod 3)
        aOffR = (aOffR == 65536u) ? 0u : aOffR + 32768u;
        aOffW = (aOffW == 65536u) ? 0u : aOffW + 32768u;
    }

    const int z = tn >> 3;
    if (z < 2) {
        // ---- Q/K epilogue: direct scatter (unchanged, verified)
        u16* dst = (z == 0) ? qo : ko;
        const int c2b = (tn & 7) * 256 + wc * 64;
        const int grb = tm * 256 + wr * 128;
#pragma unroll
    for (int mf = 0; mf < 8; mf++)
#pragma unroll
        for (int nf = 0; nf < 4; nf++)
#pragma unroll
            for (int r = 0; r < 4; r++) {
                int gr = grb + mf * 16 + q4 * 4 + r;
                int c2 = c2b + nf * 16 + lr;
                int b_ = gr >> 11, n_ = gr & (N - 1);
                int head = c2 >> 7, dcol = c2 & 127;
                dst[((size_t)(b_ * H + head) * N + n_) * DH + dcol] = f2b(acc[mf][nf][r]);
            }
    } else {
        // ---- V epilogue: LDS transpose + inverse-kappa2, coalesced vt write.
        __syncthreads();  // waves may still be reading A/B bufs of tile 31
        char* Vl = (char*)lds;  // 128 KB of the 160 KB
#pragma unroll
        for (int mf = 0; mf < 8; mf++) {
            const int granbase = wr * 32 + (mf >> 2) * 16 + ((mf & 3) >> 1) * 8
                               + ((mf & 3) & 1) + 2 * q4;
#pragma unroll
            for (int nf = 0; nf < 4; nf++) {
                int row = wc * 64 + nf * 16 + lr;
                union { u16 u[4]; unsigned long long qv; } pk;
#pragma unroll
                for (int r = 0; r < 4; r++) pk.u[r] = f2b(acc[mf][nf][r]);
                int gran = granbase ^ (row & 7);
                *(unsigned long long*)(Vl + row * 512 + gran * 8) = pk.qv;
            }
        }
        __syncthreads();
        // read out: one wave = one row (64 granules), 8B/lane, coalesced store
        const int bhb = (tm >> 3) * 16 + 2 * (tn & 7);
        const int nbase = (tm & 7) * 256;
#pragma unroll
        for (int pp = 0; pp < 32; pp++) {
            int idx = pp * 512 + t;
            int row = idx >> 6, g = idx & 63;
            unsigned long long v =
                *(const unsigned long long*)(Vl + row * 512 + ((g ^ (row & 7)) * 8));
            int bh = bhb + (row >> 7), dd = row & 127;
            *(unsigned long long*)&vo[((size_t)bh * DH + dd) * N + nbase + g * 4] = v;
        }
    }
#undef STAGE_A
#undef STAGE_B
#undef BAR
#undef DSR
}

// ---------------------------------------------------------------- attn
// v6 = verified r9-v3 (session-best, 439us total) + s_setprio around MFMA
// clusters. v3: in-register P, 4 waves x 32 q-rows, all 64 keys/wave,
// o[2][8]=64 acc (no spill), K/V double-buffer, 1 barrier/tile, Vt kappa2.
// r11 lesson: rt=4/1-block-per-CU halves LDS reads but kills TLP (occupancy
// 11% -> 190us); v3's 2 blocks/CU (2 waves/SIMD) is the overlap sweet spot.
// setprio evidence: m191 attn +4-7%; prerequisite (wave phase diversity)
// holds — the 2 co-resident blocks run unsynchronized.
#define FMAX2 17.312340491f   // 12 * log2(e)
__global__ __launch_bounds__(256, 2) void attn_kernel(const u16* __restrict__ q,
                                                      const u16* __restrict__ k,
                                                      const u16* __restrict__ vt,
                                                      float* __restrict__ out) {
    // LDS: Ks[2][64 key][128 d] at 0 (32KB, 16B-slot swz ^(row&15))
    //      Vts[2][128 dd][64 kappa2] at 32768 (32KB, 8-slot swz ^(dd&7))
    //      epilogue: Ls[128] f32 aliases bytes 0..512 (K buf0, dead by then)
    __shared__ __align__(16) char smem[65536];   // 64 KB -> 2 blocks/CU

    const int beta = blockIdx.x;                  // 0..1023
    const int bh = (beta & 7) + 8 * (beta >> 7);  // one head's q-tiles -> one XCD
    const int qt = (beta >> 3) & 15;
    const int t = threadIdx.x;
    const int w = t >> 6, lane = t & 63;          // w = row quarter (32 rows)
    const int q4 = lane >> 4, lr = lane & 15;

    // Q fragments: rows 32w+16rt+lr, d = 32ks+8q4 (B-operand of swapped S)
    const size_t qbase = ((size_t)bh * N + (size_t)qt * 128) * DH;
    short8 af[2][4];
#pragma unroll
    for (int rt = 0; rt < 2; rt++)
#pragma unroll
        for (int ks = 0; ks < 4; ks++)
            af[rt][ks] = *(const short8*)&q[qbase + (size_t)(32 * w + 16 * rt + lr) * DH
                                            + ks * 32 + q4 * 8];

    float lrow[2] = {0.f, 0.f};
    floatx4 o[2][8];
#pragma unroll
    for (int rt = 0; rt < 2; rt++)
#pragma unroll
        for (int cv = 0; cv < 8; cv++) o[rt][cv] = (floatx4){0.f, 0.f, 0.f, 0.f};

    // staging source offsets (pre-swizzled; 16B granules)
    const u16* kpB = k + (size_t)bh * N * DH;
    const u16* vpB = vt + (size_t)bh * DH * N;
    unsigned koff[4], voff[4];
#pragma unroll
    for (int c = 0; c < 4; c++) {
        int grp = 4 * w + c;
        int krow = 4 * grp + (lane >> 4);
        int kg = (lane & 15) ^ (krow & 15);
        koff[c] = (unsigned)(krow * DH + kg * 8);
        int vrow = 8 * grp + (lane >> 3);
        int vg = (lane & 7) ^ (vrow & 7);
        voff[c] = (unsigned)(vrow * N + vg * 8);
    }

    // hoisted LDS read addresses (buffer 0); toggled ^16384 per tile.
    unsigned kaddr[4];
#pragma unroll
    for (int ks = 0; ks < 4; ks++)
        kaddr[ks] = (unsigned)(lr * 256 + (((4 * ks + q4) ^ lr) * 16));
    unsigned vaddr[2];
#pragma unroll
    for (int a = 0; a < 2; a++)
        vaddr[a] = (unsigned)(32768 + lr * 128 + (((4 * a + q4) ^ (lr & 7)) * 16));

    // prologue: stage tile 0 into buffer 0
#pragma unroll
    for (int c = 0; c < 4; c++) {
        async16(kpB + koff[c], smem + (4 * w + c) * 1024);
        async16(vpB + voff[c], smem + 32768 + (4 * w + c) * 1024);
    }

    for (int kt = 0; kt < NT; kt++) {
        __syncthreads();  // vmcnt(0)+barrier: K/V(kt) visible; other buffer free

        // prefetch kt+1 (in flight until next barrier's drain)
        if (kt + 1 < NT) {
            const int nb = (kt + 1) & 1;
#pragma unroll
            for (int c = 0; c < 4; c++) {
                async16(kpB + koff[c] + (unsigned)(kt + 1) * 64 * DH,
                        smem + nb * 16384 + (4 * w + c) * 1024);
                async16(vpB + voff[c] + (unsigned)(kt + 1) * 64,
                        smem + 32768 + nb * 16384 + (4 * w + c) * 1024);
            }
        }

        // ---- S^T = K Q^T + fused softmax (P stays in registers)
        unsigned paw[2][4][2];  // [rt][ct][r-pair]
#pragma unroll
        for (int ct = 0; ct < 4; ct++) {
            short8 bf[4];
#pragma unroll
            for (int ks = 0; ks < 4; ks++)
                bf[ks] = *(const short8*)(smem + kaddr[ks] + ct * 4096);
            __builtin_amdgcn_s_setprio(1);
#pragma unroll
            for (int rt = 0; rt < 2; rt++) {
                floatx4 s = (floatx4){0.f, 0.f, 0.f, 0.f};
#pragma unroll
                for (int ks = 0; ks < 4; ks++) s = mfma16(bf[ks], af[rt][ks], s);
                float p0 = EXP2(s[0] - FMAX2), p1 = EXP2(s[1] - FMAX2);
                float p2 = EXP2(s[2] - FMAX2), p3 = EXP2(s[3] - FMAX2);
                lrow[rt] += (p0 + p1) + (p2 + p3);
                paw[rt][ct][0] = (unsigned)f2b(p0) | ((unsigned)f2b(p1) << 16);
                paw[rt][ct][1] = (unsigned)f2b(p2) | ((unsigned)f2b(p3) << 16);
            }
            __builtin_amdgcn_s_setprio(0);
        }
        // pack PA[rt][a]: element j = key 32a + 16(j>>2) + 4q4 + (j&3)
        short8 PA[2][2];
#pragma unroll
        for (int rt = 0; rt < 2; rt++)
#pragma unroll
            for (int a = 0; a < 2; a++) {
                union { unsigned uu[4]; short8 s8; } cv_;
                cv_.uu[0] = paw[rt][2 * a][0];     cv_.uu[1] = paw[rt][2 * a][1];
                cv_.uu[2] = paw[rt][2 * a + 1][0]; cv_.uu[3] = paw[rt][2 * a + 1][1];
                PA[rt][a] = cv_.s8;
            }

        // ---- PV: o[rt][ctv] += sum_a PA[rt][a] x V_a (one b128 per (ctv,a))
        __builtin_amdgcn_s_setprio(1);
#pragma unroll
        for (int ctv = 0; ctv < 8; ctv++) {
#pragma unroll
            for (int a = 0; a < 2; a++) {
                short8 bv = *(const short8*)(smem + vaddr[a] + ctv * 2048);
#pragma unroll
                for (int rt = 0; rt < 2; rt++)
                    o[rt][ctv] = mfma16(PA[rt][a], bv, o[rt][ctv]);
            }
        }
        __builtin_amdgcn_s_setprio(0);

        // toggle double buffers
#pragma unroll
        for (int ks = 0; ks < 4; ks++) kaddr[ks] ^= 16384u;
        vaddr[0] ^= 16384u; vaddr[1] ^= 16384u;
    }

    // ---- epilogue: row sums; q4-butterfly completes 64 keys; redistribute
    float* Ls = (float*)smem;  // [128] aliases kbuf0 (dead by now)
#pragma unroll
    for (int rt = 0; rt < 2; rt++) {
        float s = lrow[rt];
        s += __shfl_xor(s, 16);
        s += __shfl_xor(s, 32);
        if (q4 == 0) Ls[32 * w + 16 * rt + lr] = s;
    }
    __syncthreads();
    const size_t obase = ((size_t)bh * N + (size_t)qt * 128) * DH;
#pragma unroll
    for (int rt = 0; rt < 2; rt++) {
        floatx4 inv4;
#pragma unroll
        for (int r = 0; r < 4; r++)
            inv4[r] = 1.f / Ls[32 * w + 16 * rt + 4 * q4 + r];
#pragma unroll
        for (int ctv = 0; ctv < 8; ctv++) {
            int dd = 16 * ctv + lr;
#pragma unroll
            for (int r = 0; r < 4; r++) {
                int row = 32 * w + 16 * rt + 4 * q4 + r;
                out[obase + (size_t)row * DH + dd] = o[rt][ctv][r] * inv4[r];
            }
        }
    }
}

// ---------------------------------------------------------------- launch
extern "C" void kernel_launch(void* const* d_in, const int* in_sizes, int n_in,
                              void* d_out, int out_size, void* d_ws, size_t ws_size,
                              hipStream_t stream) {
    const float* x  = (const float*)d_in[0];
    const float* Wq = (const float*)d_in[1];
    const float* Wk = (const float*)d_in[2];
    const float* Wv = (const float*)d_in[3];
    float* out = (float*)d_out;
    char* ws = (char*)d_ws;

    u16* xb = (u16*)(ws);                  // 32 MB  bf16 X
    u16* wt = (u16*)(ws + 33554432);       // 24 MB  bf16 W^T x3 (Wq scaled)
    u16* qb = (u16*)(ws + 58720256);       // 32 MB  Q bf16 [bh][n][d]
    u16* kb = (u16*)(ws + 92274688);       // 32 MB  K bf16 [bh][n][d]
    u16* vtb = (u16*)(ws + 125829120);     // 32 MB  V^T kappa2 [bh][d][n] (direct)

    cvt_fused<<<dim3(11264), dim3(256), 0, stream>>>(x, Wq, Wk, Wv, xb, wt);
    qkv_gemm<<<dim3(768), dim3(512), 0, stream>>>(xb, wt, qb, kb, vtb);
    attn_kernel<<<dim3(1024), dim3(256), 0, stream>>>(qb, kb, vtb, out);
}